// Round 15
// baseline (1157.530 us; speedup 1.0000x reference)
//
#include <hip/hip_runtime.h>
#include <hip/hip_bf16.h>

#define ALPHA 0.2f
#define L2E 1.4426950408889634f

constexpr int Nn = 4096;
constexpr int FIN = 256;
constexpr int FOUT = 128;
constexpr int JC = 8;    // j-split for k3
constexpr int JQ = 512;  // j per k3 block
constexpr int NCH = 8;   // 64-j chunks per k3 block
constexpr long long SLAB = 2097152;  // 4*4096*128 elems per partial slab

// Diagnostic repetition factors (semantics-preserving).
constexpr int REP1 = 48;  // k1b  ~4us/rep  -> ~190us dispatch
constexpr int REP2 = 5;   // k2  ~45us/rep  -> ~225us dispatch
constexpr int REP3 = 16;  // k3  ~36us/rep  -> ~580us dispatch

typedef __attribute__((ext_vector_type(8))) short short8;
typedef __attribute__((ext_vector_type(8))) unsigned short ushort8;
typedef __attribute__((ext_vector_type(4))) float f32x4;
typedef __attribute__((ext_vector_type(4))) int int4v;
typedef __attribute__((ext_vector_type(4))) unsigned int uint4v;

__device__ __forceinline__ unsigned short f2bf(float x) {
  unsigned int u = __float_as_uint(x);
  unsigned int r = (u + 0x7fffu + ((u >> 16) & 1u)) >> 16;
  return (unsigned short)r;
}

__device__ __forceinline__ float bf2f(unsigned short v) {
  return __uint_as_float(((unsigned)v) << 16);
}

__device__ __forceinline__ void gload16(const void* g, void* l) {
  auto lp = (__attribute__((address_space(3))) void*)l;
  auto gp = (const __attribute__((address_space(1))) void*)g;
  __builtin_amdgcn_global_load_lds(gp, lp, 16, 0, 0);
}

// ---------------------------------------------------------------------------
// k0: WT bf16 [i=128][k=256] from W f32 [k][i] (LDS transpose). Grid 8.
// ---------------------------------------------------------------------------
__global__ __launch_bounds__(256) void k0_prep(
    const float* __restrict__ W, unsigned short* __restrict__ WT) {
  __shared__ float lw[32][132];
  int t = threadIdx.x;
  int kc0 = blockIdx.x * 32;
#pragma unroll
  for (int m = 0; m < 4; ++m) {
    int idx = t * 16 + m * 4;
    f32x4 v = *(const f32x4*)(W + kc0 * 128 + idx);
    int k = idx >> 7, i0 = idx & 127;
    *(f32x4*)&lw[k][i0] = v;
  }
  __syncthreads();
  int i = t >> 1, half = t & 1;
  unsigned short pk[16];
#pragma unroll
  for (int kk = 0; kk < 16; ++kk) pk[kk] = f2bf(lw[half * 16 + kk][i]);
  ushort8* dst = (ushort8*)(WT + i * 256 + kc0 + half * 16);
  dst[0] = *(ushort8*)&pk[0];
  dst[1] = *(ushort8*)&pk[8];
}

// ---------------------------------------------------------------------------
// k1b: Wh via mfma_16x16x32_bf16. DIAGNOSTIC: xREP1.
// ---------------------------------------------------------------------------
__global__ __launch_bounds__(256) void k1b_wh(
    const float* __restrict__ h, const unsigned short* __restrict__ WT,
    const float* __restrict__ a, unsigned short* __restrict__ whT,
    float* __restrict__ s1L, float* __restrict__ s2L) {
  __shared__ __align__(16) char smem[36864];
  int t = threadIdx.x;
  int w = t >> 6, l = t & 63, g = l >> 4, r = l & 15;
  int r0 = blockIdx.x * 16;
  int b = r0 >> 12, nbase = r0 & 4095;

#pragma unroll 1
  for (int rep = 0; rep < REP1; ++rep) {
    asm volatile("" ::: "memory");
    f32x4 acc[2];
    acc[0] = (f32x4){0.f, 0.f, 0.f, 0.f};
    acc[1] = (f32x4){0.f, 0.f, 0.f, 0.f};

    for (int kc = 0; kc < 2; ++kc) {
      __syncthreads();
      {
        int row = t >> 4, sec = t & 15;
        const f32x4* src = (const f32x4*)(h + (long long)(r0 + row) * 256 +
                                          kc * 128 + sec * 8);
        f32x4 v0 = src[0], v1 = src[1];
        unsigned int pk[4];
        pk[0] = ((unsigned)f2bf(v0.y) << 16) | f2bf(v0.x);
        pk[1] = ((unsigned)f2bf(v0.w) << 16) | f2bf(v0.z);
        pk[2] = ((unsigned)f2bf(v1.y) << 16) | f2bf(v1.x);
        pk[3] = ((unsigned)f2bf(v1.w) << 16) | f2bf(v1.z);
        *(ushort8*)(smem + row * 256 + ((sec ^ (row & 7)) << 4)) =
            *(ushort8*)pk;
      }
      {
        int i = t >> 1, pt = t & 1;
        const ushort8* src =
            (const ushort8*)(WT + i * 256 + kc * 128 + pt * 64);
#pragma unroll
        for (int m = 0; m < 8; ++m) {
          ushort8 v = src[m];
          int slot = pt * 8 + m;
          *(ushort8*)(smem + 4096 + i * 256 + ((slot ^ (i & 7)) << 4)) = v;
        }
      }
      __syncthreads();
#pragma unroll
      for (int kk = 0; kk < 4; ++kk) {
        short8 af =
            *(const short8*)(smem + r * 256 + (((kk * 4 + g) ^ (r & 7)) << 4));
#pragma unroll
        for (int s = 0; s < 2; ++s) {
          int i = w * 32 + s * 16 + r;
          short8 bf = *(const short8*)(smem + 4096 + i * 256 +
                                       (((kk * 4 + g) ^ (i & 7)) << 4));
          acc[s] =
              __builtin_amdgcn_mfma_f32_16x16x32_bf16(af, bf, acc[s], 0, 0, 0);
        }
      }
    }

    __syncthreads();
    unsigned short* tb = (unsigned short*)smem;  // [128][25]
#pragma unroll
    for (int s = 0; s < 2; ++s)
#pragma unroll
      for (int q = 0; q < 4; ++q)
        tb[(w * 32 + s * 16 + r) * 25 + g * 4 + q] = f2bf(acc[s][q]);
    __syncthreads();

    {
      int i = t >> 1, half = t & 1;
      ushort8 v = *(const ushort8*)(tb + i * 25 + half * 8);
      *(ushort8*)(whT + (((long long)(b * 128 + i)) << 12) + nbase +
                  half * 8) = v;
    }
    {
      int n = t >> 4, seg = t & 15;
      f32x4 a10 = *(const f32x4*)(a + seg * 8);
      f32x4 a11 = *(const f32x4*)(a + seg * 8 + 4);
      f32x4 a20 = *(const f32x4*)(a + 128 + seg * 8);
      f32x4 a21 = *(const f32x4*)(a + 128 + seg * 8 + 4);
      float v1 = 0.f, v2 = 0.f;
#pragma unroll
      for (int m = 0; m < 8; ++m) {
        float wh = bf2f(tb[(seg * 8 + m) * 25 + n]);
        float c1 = (m < 4) ? a10[m] : a11[m - 4];
        float c2 = (m < 4) ? a20[m] : a21[m - 4];
        v1 += wh * c1;
        v2 += wh * c2;
      }
#pragma unroll
      for (int off = 8; off; off >>= 1) {
        v1 += __shfl_xor(v1, off);
        v2 += __shfl_xor(v2, off);
      }
      if (seg == 0) {
        s1L[r0 + n] = v1 * L2E;
        s2L[r0 + n] = v2 * L2E;
      }
    }
    __syncthreads();
  }
}

// ---------------------------------------------------------------------------
// k2: block-per-row single-pass softmax + mask pack. DIAGNOSTIC: xREP2.
// ---------------------------------------------------------------------------
__global__ __launch_bounds__(256) void k2_stats(
    const int* __restrict__ adj, const float* __restrict__ s1L,
    const float* __restrict__ s2L, float2* __restrict__ st2,
    unsigned long long* __restrict__ mask64) {
  __shared__ unsigned int mwords[128];
  __shared__ float wsum[4];
  int row = blockIdx.x;
  int b = row >> 12;
  int t = threadIdx.x;
  const int4v* arow = (const int4v*)(adj + (long long)row * Nn);
  const f32x4* s2v = (const f32x4*)(s2L + (b << 12));

#pragma unroll 1
  for (int rep = 0; rep < REP2; ++rep) {
    asm volatile("" ::: "memory");
    float s1j = s1L[row];
    float sum = 0.f;
#pragma unroll
    for (int q = 0; q < 4; ++q) {
      int4v av = __builtin_nontemporal_load(arow + q * 256 + t);
      f32x4 sv = s2v[q * 256 + t];
      unsigned nib = 0;
#pragma unroll
      for (int c = 0; c < 4; ++c) {
        float u = s1j + sv[c];
        float vL = fmaxf(u, ALPHA * u);
        float e = exp2f(vL);
        sum = fmaf((float)av[c], e, sum);  // adj in {0,1}
        nib |= ((unsigned)av[c]) << c;
      }
      unsigned n1 = nib | (__shfl_xor(nib, 1) << 4);
      unsigned n2 = n1 | (__shfl_xor(n1, 2) << 8);
      unsigned n4 = n2 | (__shfl_xor(n2, 4) << 16);
      if ((t & 7) == 0) mwords[q * 32 + (t >> 3)] = n4;
    }
#pragma unroll
    for (int off = 32; off; off >>= 1) sum += __shfl_xor(sum, off);
    if ((t & 63) == 0) wsum[t >> 6] = sum;
    __syncthreads();
    if (t < 64) {
      unsigned long long mv = *(unsigned long long*)&mwords[t * 2];
      mask64[((long long)row << 6) + t] = mv;
    }
    if (t == 0) {
      float S = wsum[0] + wsum[1] + wsum[2] + wsum[3];
      float negc = (S > 0.f) ? -log2f(S) : -1.0e30f;
      st2[row] = make_float2(exp2f(s1j + negc), exp2f(ALPHA * s1j + negc));
    }
    __syncthreads();
  }
}

// ---------------------------------------------------------------------------
// k3: bf16 partial[jc][b][k][i] = sum_{j in eighth} p[j,k]*Wh[j,i].
// DIAGNOSTIC: xREP3 (idempotent; final barrier of chunk loop fences LDS).
// ---------------------------------------------------------------------------
__global__ __launch_bounds__(512, 6) void k3_pv(
    const unsigned short* __restrict__ whT, const float2* __restrict__ st2,
    const unsigned long long* __restrict__ mask64,
    const float* __restrict__ s2L, unsigned short* __restrict__ pbuf) {
  __shared__ __align__(16) char smem[45056];
  unsigned int* mkpl = (unsigned int*)(smem + 32768);  // [4][512]
  float2* stl = (float2*)(smem + 40960);               // [512]

  int t = threadIdx.x;
  int orig = blockIdx.x;
  int x = orig & 7, mm = orig >> 3;
  int b = x >> 1;
  int kt = ((x & 1) << 4) | (mm & 15);  // 0..31
  int jc = mm >> 4;                     // 0..7
  int w = t >> 6, l = t & 63;
  int lh = l >> 4;
  int lo = l & 15;
  int ks = w;
  int jq0 = jc * JQ;
  long long brow = (long long)(b << 12);
  int k0g = kt << 7;
  float z1 = s2L[brow + k0g + ks * 16 + lo];
  float F1 = exp2f(z1);
  float F2 = exp2f(ALPHA * z1);
  int sh31 = 31 - (((ks & 1) << 4) + lo);
  int wsel = ks >> 1;

  const unsigned short* whTb = whT + ((long long)b << 19);
  int gi = t & 127;
  const unsigned short* wsrcL =
      whTb + (long long)gi * 4096 + jq0 + (t >> 7) * 8;
  const unsigned short* wsrcH = wsrcL + 32;

#pragma unroll 1
  for (int rep = 0; rep < REP3; ++rep) {
    asm volatile("" ::: "memory");
    __syncthreads();
    // stage-once: stl, mask planes, whT chunk 0
    if (t < 256) gload16(st2 + brow + jq0 + t * 2, (char*)stl + t * 16);
    {
      uint4v mrow = *(const uint4v*)((const char*)(mask64 +
                                                   ((brow + jq0 + t) << 6)) +
                                     kt * 16);
      mkpl[0 * 512 + t] = mrow[0];
      mkpl[1 * 512 + t] = mrow[1];
      mkpl[2 * 512 + t] = mrow[2];
      mkpl[3 * 512 + t] = mrow[3];
    }
    gload16(wsrcL, smem + t * 16);
    gload16(wsrcH, smem + (t + 512) * 16);
    __syncthreads();

    f32x4 acc[8];
#pragma unroll
    for (int q = 0; q < 8; ++q) acc[q] = (f32x4){0.f, 0.f, 0.f, 0.f};

    const unsigned int* mkw = mkpl + wsel * 512;
    for (int ch = 0; ch < NCH; ++ch) {
      int cur = ch & 1;
      if (ch + 1 < NCH) {
        char* nb = smem + (cur ^ 1) * 16384;
        gload16(wsrcL + (ch + 1) * 64, nb + t * 16);
        gload16(wsrcH + (ch + 1) * 64, nb + (t + 512) * 16);
      }
      char* wb = smem + cur * 16384;
#pragma unroll
      for (int s = 0; s < 2; ++s) {
        int jb = ch * 64 + s * 32 + lh * 8;
        uint4v mw0 = *(const uint4v*)(mkw + jb);
        uint4v mw1 = *(const uint4v*)(mkw + jb + 4);
        const f32x4* stp = (const f32x4*)(stl + jb);
        f32x4 sA = stp[0], sB = stp[1], sC = stp[2], sD = stp[3];
        short8 af;
#pragma unroll
        for (int e = 0; e < 8; ++e) {
          f32x4 sv = (e < 2) ? sA : (e < 4) ? sB : (e < 6) ? sC : sD;
          float E1 = (e & 1) ? sv.z : sv.x;
          float E2 = (e & 1) ? sv.w : sv.y;
          unsigned mv = (e < 4) ? mw0[e] : mw1[e - 4];
          float p = fmaxf(E1 * F1, E2 * F2);
          int msk = ((int)(mv << sh31)) >> 31;
          unsigned pu = __float_as_uint(p) & (unsigned)msk;
          __hip_bfloat16 hb = __float2bfloat16(__uint_as_float(pu));
          af[e] = *(short*)&hb;
        }
        int gb = (s * 4 + lh) * 128;
#pragma unroll
        for (int q = 0; q < 8; ++q) {
          short8 bv = *(const short8*)(wb + ((gb + q * 16 + lo) << 4));
          acc[q] =
              __builtin_amdgcn_mfma_f32_16x16x32_bf16(af, bv, acc[q], 0, 0, 0);
        }
      }
      __syncthreads();
    }

    unsigned short* pb = pbuf + (long long)jc * SLAB + ((brow + k0g) << 7);
#pragma unroll
    for (int q = 0; q < 8; ++q) {
#pragma unroll
      for (int r = 0; r < 4; ++r) {
        int kl = ks * 16 + lh * 4 + r;
        pb[kl * 128 + q * 16 + lo] = f2bf(acc[q][r]);
      }
    }
  }
}

// ---------------------------------------------------------------------------
// k4: out = elu(sum_jc bf16 partial). Grid 1024 x 256, 8 elems/thread.
// ---------------------------------------------------------------------------
__global__ __launch_bounds__(256) void k4_reduce(
    const unsigned short* __restrict__ pbuf, float* __restrict__ out) {
  int orig = blockIdx.x;
  int n = (orig & 7) * 128 + (orig >> 3);
  int base = (n * 256 + threadIdx.x) * 8;
  float s[8] = {0.f, 0.f, 0.f, 0.f, 0.f, 0.f, 0.f, 0.f};
#pragma unroll
  for (int sl = 0; sl < JC; ++sl) {
    ushort8 v = *(const ushort8*)(pbuf + (long long)sl * SLAB + base);
#pragma unroll
    for (int e = 0; e < 8; ++e)
      s[e] += __uint_as_float(((unsigned)(unsigned short)v[e]) << 16);
  }
  f32x4 o0, o1;
#pragma unroll
  for (int e = 0; e < 8; ++e) {
    float xv = s[e];
    float y = xv > 0.f ? xv : expm1f(xv);
    if (e < 4) o0[e] = y; else o1[e - 4] = y;
  }
  *(f32x4*)(out + base) = o0;
  *(f32x4*)(out + base + 4) = o1;
}

extern "C" void kernel_launch(void* const* d_in, const int* in_sizes, int n_in,
                              void* d_out, int out_size, void* d_ws,
                              size_t ws_size, hipStream_t stream) {
  const float* h = (const float*)d_in[0];
  const int* adj = (const int*)d_in[1];
  const float* W = (const float*)d_in[2];
  const float* a = (const float*)d_in[3];
  float* out = (float*)d_out;

  char* ws = (char*)d_ws;
  unsigned short* WT = (unsigned short*)ws;                  // 64 KB
  unsigned short* whT = (unsigned short*)(ws + (1 << 20));   // 4 MB
  float* s1L = (float*)(ws + (5 << 20));                     // 64 KB
  float* s2L = s1L + 16384;                                  // 64 KB
  float2* st2 = (float2*)(ws + (5 << 20) + (128 << 10));     // 128 KB
  unsigned long long* mask64 =
      (unsigned long long*)(ws + (6 << 20));                 // 8 MB
  unsigned short* pbuf = (unsigned short*)(ws + (16 << 20)); // 32 MB bf16

  hipLaunchKernelGGL(k0_prep, dim3(8), dim3(256), 0, stream, W, WT);
  hipLaunchKernelGGL(k1b_wh, dim3(1024), dim3(256), 0, stream, h, WT, a, whT,
                     s1L, s2L);
  hipLaunchKernelGGL(k2_stats, dim3(16384), dim3(256), 0, stream, adj, s1L,
                     s2L, st2, mask64);
  hipLaunchKernelGGL(k3_pv, dim3(1024), dim3(512), 0, stream, whT, st2,
                     mask64, s2L, pbuf);
  hipLaunchKernelGGL(k4_reduce, dim3(1024), dim3(256), 0, stream, pbuf, out);
}

// Round 16
// 108.984 us; speedup vs baseline: 10.6211x; 10.6211x over previous
//
#include <hip/hip_runtime.h>
#include <hip/hip_bf16.h>

#define ALPHA 0.2f
#define L2E 1.4426950408889634f

constexpr int Nn = 4096;
constexpr int FIN = 256;
constexpr int FOUT = 128;
constexpr int JC = 8;    // j-split for k3
constexpr int JQ = 512;  // j per k3 block
constexpr int NCH = 16;  // 32-j chunks per k3 block
constexpr long long SLAB = 2097152;  // 4*4096*128 elems per partial slab

typedef __attribute__((ext_vector_type(8))) short short8;
typedef __attribute__((ext_vector_type(8))) unsigned short ushort8;
typedef __attribute__((ext_vector_type(4))) float f32x4;
typedef __attribute__((ext_vector_type(4))) int int4v;
typedef __attribute__((ext_vector_type(4))) unsigned int uint4v;

__device__ __forceinline__ unsigned short f2bf(float x) {
  unsigned int u = __float_as_uint(x);
  unsigned int r = (u + 0x7fffu + ((u >> 16) & 1u)) >> 16;
  return (unsigned short)r;
}

__device__ __forceinline__ float bf2f(unsigned short v) {
  return __uint_as_float(((unsigned)v) << 16);
}

__device__ __forceinline__ void gload16(const void* g, void* l) {
  auto lp = (__attribute__((address_space(3))) void*)l;
  auto gp = (const __attribute__((address_space(1))) void*)g;
  __builtin_amdgcn_global_load_lds(gp, lp, 16, 0, 0);
}

// ---------------------------------------------------------------------------
// k0: WT bf16 [i=128][k=256] from W f32 [k][i] (LDS transpose). Grid 8.
// ---------------------------------------------------------------------------
__global__ __launch_bounds__(256) void k0_prep(
    const float* __restrict__ W, unsigned short* __restrict__ WT) {
  __shared__ float lw[32][132];
  int t = threadIdx.x;
  int kc0 = blockIdx.x * 32;
#pragma unroll
  for (int m = 0; m < 4; ++m) {
    int idx = t * 16 + m * 4;
    f32x4 v = *(const f32x4*)(W + kc0 * 128 + idx);
    int k = idx >> 7, i0 = idx & 127;
    *(f32x4*)&lw[k][i0] = v;
  }
  __syncthreads();
  int i = t >> 1, half = t & 1;
  unsigned short pk[16];
#pragma unroll
  for (int kk = 0; kk < 16; ++kk) pk[kk] = f2bf(lw[half * 16 + kk][i]);
  ushort8* dst = (ushort8*)(WT + i * 256 + kc0 + half * 16);
  dst[0] = *(ushort8*)&pk[0];
  dst[1] = *(ushort8*)&pk[8];
}

// ---------------------------------------------------------------------------
// k1b: Wh via mfma_16x16x32_bf16. 16-row blocks, grid 1024.
// Emits whT bf16 [b][i=128][n=4096] AND s1L/s2L (x log2 e).
// ---------------------------------------------------------------------------
__global__ __launch_bounds__(256) void k1b_wh(
    const float* __restrict__ h, const unsigned short* __restrict__ WT,
    const float* __restrict__ a, unsigned short* __restrict__ whT,
    float* __restrict__ s1L, float* __restrict__ s2L) {
  __shared__ __align__(16) char smem[36864];
  int t = threadIdx.x;
  int w = t >> 6, l = t & 63, g = l >> 4, r = l & 15;
  int r0 = blockIdx.x * 16;
  int b = r0 >> 12, nbase = r0 & 4095;

  f32x4 acc[2];
  acc[0] = (f32x4){0.f, 0.f, 0.f, 0.f};
  acc[1] = (f32x4){0.f, 0.f, 0.f, 0.f};

  for (int kc = 0; kc < 2; ++kc) {
    __syncthreads();
    {
      int row = t >> 4, sec = t & 15;
      const f32x4* src =
          (const f32x4*)(h + (long long)(r0 + row) * 256 + kc * 128 + sec * 8);
      f32x4 v0 = src[0], v1 = src[1];
      unsigned int pk[4];
      pk[0] = ((unsigned)f2bf(v0.y) << 16) | f2bf(v0.x);
      pk[1] = ((unsigned)f2bf(v0.w) << 16) | f2bf(v0.z);
      pk[2] = ((unsigned)f2bf(v1.y) << 16) | f2bf(v1.x);
      pk[3] = ((unsigned)f2bf(v1.w) << 16) | f2bf(v1.z);
      *(ushort8*)(smem + row * 256 + ((sec ^ (row & 7)) << 4)) = *(ushort8*)pk;
    }
    {
      int i = t >> 1, pt = t & 1;
      const ushort8* src = (const ushort8*)(WT + i * 256 + kc * 128 + pt * 64);
#pragma unroll
      for (int m = 0; m < 8; ++m) {
        ushort8 v = src[m];
        int slot = pt * 8 + m;
        *(ushort8*)(smem + 4096 + i * 256 + ((slot ^ (i & 7)) << 4)) = v;
      }
    }
    __syncthreads();
#pragma unroll
    for (int kk = 0; kk < 4; ++kk) {
      short8 af =
          *(const short8*)(smem + r * 256 + (((kk * 4 + g) ^ (r & 7)) << 4));
#pragma unroll
      for (int s = 0; s < 2; ++s) {
        int i = w * 32 + s * 16 + r;
        short8 bf = *(const short8*)(smem + 4096 + i * 256 +
                                     (((kk * 4 + g) ^ (i & 7)) << 4));
        acc[s] =
            __builtin_amdgcn_mfma_f32_16x16x32_bf16(af, bf, acc[s], 0, 0, 0);
      }
    }
  }

  __syncthreads();
  unsigned short* tb = (unsigned short*)smem;  // [128][25]
#pragma unroll
  for (int s = 0; s < 2; ++s)
#pragma unroll
    for (int q = 0; q < 4; ++q)
      tb[(w * 32 + s * 16 + r) * 25 + g * 4 + q] = f2bf(acc[s][q]);
  __syncthreads();

  {
    int i = t >> 1, half = t & 1;
    ushort8 v = *(const ushort8*)(tb + i * 25 + half * 8);
    *(ushort8*)(whT + (((long long)(b * 128 + i)) << 12) + nbase + half * 8) =
        v;
  }
  {
    int n = t >> 4, seg = t & 15;
    f32x4 a10 = *(const f32x4*)(a + seg * 8);
    f32x4 a11 = *(const f32x4*)(a + seg * 8 + 4);
    f32x4 a20 = *(const f32x4*)(a + 128 + seg * 8);
    f32x4 a21 = *(const f32x4*)(a + 128 + seg * 8 + 4);
    float v1 = 0.f, v2 = 0.f;
#pragma unroll
    for (int m = 0; m < 8; ++m) {
      float wh = bf2f(tb[(seg * 8 + m) * 25 + n]);
      float c1 = (m < 4) ? a10[m] : a11[m - 4];
      float c2 = (m < 4) ? a20[m] : a21[m - 4];
      v1 += wh * c1;
      v2 += wh * c2;
    }
#pragma unroll
    for (int off = 8; off; off >>= 1) {
      v1 += __shfl_xor(v1, off);
      v2 += __shfl_xor(v2, off);
    }
    if (seg == 0) {
      s1L[r0 + n] = v1 * L2E;
      s2L[r0 + n] = v2 * L2E;
    }
  }
}

// ---------------------------------------------------------------------------
// k2: block-per-row, coalesced NT int4 adj loads, single-pass no-max softmax
// in exp2 domain; mask via shfl_xor nibble merge. st2[row] = {E1, E2} where
// E1 = exp2(s1L+negc), E2 = exp2(ALPHA*s1L+negc) -- factorized for k3.
// ---------------------------------------------------------------------------
__global__ __launch_bounds__(256) void k2_stats(
    const int* __restrict__ adj, const float* __restrict__ s1L,
    const float* __restrict__ s2L, float2* __restrict__ st2,
    unsigned long long* __restrict__ mask64) {
  __shared__ unsigned int mwords[128];
  __shared__ float wsum[4];
  int row = blockIdx.x;
  int b = row >> 12;
  int t = threadIdx.x;
  float s1j = s1L[row];
  const int4v* arow = (const int4v*)(adj + (long long)row * Nn);
  const f32x4* s2v = (const f32x4*)(s2L + (b << 12));

  float sum = 0.f;
#pragma unroll
  for (int q = 0; q < 4; ++q) {
    int4v av = __builtin_nontemporal_load(arow + q * 256 + t);
    f32x4 sv = s2v[q * 256 + t];
    unsigned nib = 0;
#pragma unroll
    for (int c = 0; c < 4; ++c) {
      float u = s1j + sv[c];
      float vL = fmaxf(u, ALPHA * u);
      float e = exp2f(vL);
      sum = fmaf((float)av[c], e, sum);  // adj in {0,1}
      nib |= ((unsigned)av[c]) << c;
    }
    unsigned n1 = nib | (__shfl_xor(nib, 1) << 4);
    unsigned n2 = n1 | (__shfl_xor(n1, 2) << 8);
    unsigned n4 = n2 | (__shfl_xor(n2, 4) << 16);
    if ((t & 7) == 0) mwords[q * 32 + (t >> 3)] = n4;
  }
#pragma unroll
  for (int off = 32; off; off >>= 1) sum += __shfl_xor(sum, off);
  if ((t & 63) == 0) wsum[t >> 6] = sum;
  __syncthreads();
  if (t < 64) {
    unsigned long long mv = *(unsigned long long*)&mwords[t * 2];
    mask64[((long long)row << 6) + t] = mv;
  }
  if (t == 0) {
    float S = wsum[0] + wsum[1] + wsum[2] + wsum[3];
    float negc = (S > 0.f) ? -log2f(S) : -1.0e30f;
    st2[row] =
        make_float2(exp2f(s1j + negc), exp2f(ALPHA * s1j + negc));
  }
}

// ---------------------------------------------------------------------------
// k3: bf16 partial[jc][b][k][i] = sum_{j in eighth} p[j,k]*Wh[j,i].
// Factorized A-build (p = max(E1*F1, E2*F2), masked). 16x16x32 MFMA,
// NCH=16, LDS 28KB. NEW: A-side operands (mask words + E-pairs) are
// register-software-pipelined one chunk ahead -- ds_reads issue before the
// chunk barrier and complete under the MFMA phase, so post-barrier A-build
// is pure VALU with no LGKM wait (R15 diag: VALU 52%, MFMA 22%, 9us stall).
// Epilogue uses __float2bfloat16 (compiler cvt, not 4-op manual RNE).
// ---------------------------------------------------------------------------
__global__ __launch_bounds__(512, 6) void k3_pv(
    const unsigned short* __restrict__ whT, const float2* __restrict__ st2,
    const unsigned long long* __restrict__ mask64,
    const float* __restrict__ s2L, unsigned short* __restrict__ pbuf) {
  __shared__ __align__(16) char smem[28672];
  unsigned int* mkpl = (unsigned int*)(smem + 16384);  // [4][512]
  float2* stl = (float2*)(smem + 24576);               // [512]

  int t = threadIdx.x;
  int orig = blockIdx.x;
  int x = orig & 7, mm = orig >> 3;
  int b = x >> 1;
  int kt = ((x & 1) << 4) | (mm & 15);  // 0..31
  int jc = mm >> 4;                     // 0..7
  int w = t >> 6, l = t & 63;
  int lh = l >> 4;   // 0..3: j-subgroup (A/B K-group)
  int lo = l & 15;   // 0..15: A-row (k) / B-col (i)
  int ks = w;        // 8 k-subs x 16
  int jq0 = jc * JQ;
  long long brow = (long long)(b << 12);
  int k0g = kt << 7;  // KT = 128
  float z1 = s2L[brow + k0g + ks * 16 + lo];
  float F1 = exp2f(z1);
  float F2 = exp2f(ALPHA * z1);
  int sh31 = 31 - (((ks & 1) << 4) + lo);
  int wsel = ks >> 1;  // u32 mask plane

  // stage-once: stl (4KB via gload16), mask planes (reg-staged scatter)
  if (t < 256) gload16(st2 + brow + jq0 + t * 2, (char*)stl + t * 16);
  {
    uint4v mrow = *(const uint4v*)((const char*)(mask64 +
                                                 ((brow + jq0 + t) << 6)) +
                                   kt * 16);
    mkpl[0 * 512 + t] = mrow[0];
    mkpl[1 * 512 + t] = mrow[1];
    mkpl[2 * 512 + t] = mrow[2];
    mkpl[3 * 512 + t] = mrow[3];
  }
  // whT chunk 0: thread t -> granule (gj=t>>7 j-oct, gi=t&127 i), linear dest
  const unsigned short* whTb = whT + ((long long)b << 19);
  int gi = t & 127;
  const unsigned short* wsrc0 =
      whTb + (long long)gi * 4096 + jq0 + (t >> 7) * 8;
  gload16(wsrc0, smem + t * 16);
  __syncthreads();

  f32x4 acc[8];
#pragma unroll
  for (int q = 0; q < 8; ++q) acc[q] = (f32x4){0.f, 0.f, 0.f, 0.f};

  const unsigned int* mkw = mkpl + wsel * 512;

  // prefetch chunk 0 A-side operands into registers
  uint4v nmw0, nmw1;
  f32x4 ns0, ns1, ns2, ns3;
  {
    int jb0 = lh * 8;
    nmw0 = *(const uint4v*)(mkw + jb0);
    nmw1 = *(const uint4v*)(mkw + jb0 + 4);
    const f32x4* stp0 = (const f32x4*)(stl + jb0);
    ns0 = stp0[0];
    ns1 = stp0[1];
    ns2 = stp0[2];
    ns3 = stp0[3];
  }

#pragma unroll
  for (int ch = 0; ch < NCH; ++ch) {
    int cur = ch & 1;
    if (ch + 1 < NCH)
      gload16(wsrc0 + (ch + 1) * 32, smem + (cur ^ 1) * 8192 + t * 16);
    char* wb = smem + cur * 8192;

    // rotate prefetched regs into current
    uint4v mw0 = nmw0, mw1 = nmw1;
    f32x4 sA = ns0, sB = ns1, sC = ns2, sD = ns3;
    // issue next chunk's A-side ds_reads (latency spans MFMAs + barrier)
    if (ch + 1 < NCH) {
      int jbn = (ch + 1) * 32 + lh * 8;
      nmw0 = *(const uint4v*)(mkw + jbn);
      nmw1 = *(const uint4v*)(mkw + jbn + 4);
      const f32x4* stpn = (const f32x4*)(stl + jbn);
      ns0 = stpn[0];
      ns1 = stpn[1];
      ns2 = stpn[2];
      ns3 = stpn[3];
    }

    short8 af;
#pragma unroll
    for (int e = 0; e < 8; ++e) {
      f32x4 sv = (e < 2) ? sA : (e < 4) ? sB : (e < 6) ? sC : sD;
      float E1 = (e & 1) ? sv.z : sv.x;
      float E2 = (e & 1) ? sv.w : sv.y;
      unsigned mv = (e < 4) ? mw0[e] : mw1[e - 4];
      float p = fmaxf(E1 * F1, E2 * F2);
      int msk = ((int)(mv << sh31)) >> 31;
      unsigned pu = __float_as_uint(p) & (unsigned)msk;
      __hip_bfloat16 hb = __float2bfloat16(__uint_as_float(pu));
      af[e] = *(short*)&hb;
    }
#pragma unroll
    for (int q = 0; q < 8; ++q) {
      short8 bv = *(const short8*)(wb + ((lh * 128 + q * 16 + lo) << 4));
      acc[q] = __builtin_amdgcn_mfma_f32_16x16x32_bf16(af, bv, acc[q], 0, 0, 0);
    }
    __syncthreads();
  }

  // store: D col = lo (i within tile), row = lh*4 + r (k within 16)
  unsigned short* pb = pbuf + (long long)jc * SLAB + ((brow + k0g) << 7);
#pragma unroll
  for (int q = 0; q < 8; ++q) {
#pragma unroll
    for (int r = 0; r < 4; ++r) {
      int kl = ks * 16 + lh * 4 + r;
      __hip_bfloat16 hb = __float2bfloat16(acc[q][r]);
      pb[kl * 128 + q * 16 + lo] = *(unsigned short*)&hb;
    }
  }
}

// ---------------------------------------------------------------------------
// k4: out = elu(sum_jc bf16 partial). Grid 1024 x 256, 8 elems/thread.
// Swizzle reads tile n from the XCD (n>>7) where k3 wrote it.
// ---------------------------------------------------------------------------
__global__ __launch_bounds__(256) void k4_reduce(
    const unsigned short* __restrict__ pbuf, float* __restrict__ out) {
  int orig = blockIdx.x;
  int n = (orig & 7) * 128 + (orig >> 3);  // bijective (1024 % 8 == 0)
  int base = (n * 256 + threadIdx.x) * 8;
  float s[8] = {0.f, 0.f, 0.f, 0.f, 0.f, 0.f, 0.f, 0.f};
#pragma unroll
  for (int sl = 0; sl < JC; ++sl) {
    ushort8 v = *(const ushort8*)(pbuf + (long long)sl * SLAB + base);
#pragma unroll
    for (int e = 0; e < 8; ++e)
      s[e] += __uint_as_float(((unsigned)(unsigned short)v[e]) << 16);
  }
  f32x4 o0, o1;
#pragma unroll
  for (int e = 0; e < 8; ++e) {
    float xv = s[e];
    float y = xv > 0.f ? xv : expm1f(xv);
    if (e < 4) o0[e] = y; else o1[e - 4] = y;
  }
  *(f32x4*)(out + base) = o0;
  *(f32x4*)(out + base + 4) = o1;
}

extern "C" void kernel_launch(void* const* d_in, const int* in_sizes, int n_in,
                              void* d_out, int out_size, void* d_ws,
                              size_t ws_size, hipStream_t stream) {
  const float* h = (const float*)d_in[0];
  const int* adj = (const int*)d_in[1];
  const float* W = (const float*)d_in[2];
  const float* a = (const float*)d_in[3];
  float* out = (float*)d_out;

  char* ws = (char*)d_ws;
  unsigned short* WT = (unsigned short*)ws;                  // 64 KB
  unsigned short* whT = (unsigned short*)(ws + (1 << 20));   // 4 MB
  float* s1L = (float*)(ws + (5 << 20));                     // 64 KB
  float* s2L = s1L + 16384;                                  // 64 KB
  float2* st2 = (float2*)(ws + (5 << 20) + (128 << 10));     // 128 KB
  unsigned long long* mask64 =
      (unsigned long long*)(ws + (6 << 20));                 // 8 MB
  unsigned short* pbuf = (unsigned short*)(ws + (16 << 20)); // 32 MB bf16

  hipLaunchKernelGGL(k0_prep, dim3(8), dim3(256), 0, stream, W, WT);
  hipLaunchKernelGGL(k1b_wh, dim3(1024), dim3(256), 0, stream, h, WT, a, whT,
                     s1L, s2L);
  hipLaunchKernelGGL(k2_stats, dim3(16384), dim3(256), 0, stream, adj, s1L,
                     s2L, st2, mask64);
  hipLaunchKernelGGL(k3_pv, dim3(1024), dim3(512), 0, stream, whT, st2,
                     mask64, s2L, pbuf);
  hipLaunchKernelGGL(k4_reduce, dim3(1024), dim3(256), 0, stream, pbuf, out);
}

// Round 17
// 106.806 us; speedup vs baseline: 10.8376x; 1.0204x over previous
//
#include <hip/hip_runtime.h>
#include <hip/hip_bf16.h>

#define ALPHA 0.2f
#define L2E 1.4426950408889634f

constexpr int Nn = 4096;
constexpr int FIN = 256;
constexpr int FOUT = 128;
constexpr int JC = 8;    // j-split for k3
constexpr int JQ = 512;  // j per k3 block
constexpr int NCH = 16;  // 32-j chunks per k3 block
constexpr long long SLAB = 2097152;  // 4*4096*128 elems per partial slab

typedef __attribute__((ext_vector_type(8))) short short8;
typedef __attribute__((ext_vector_type(8))) unsigned short ushort8;
typedef __attribute__((ext_vector_type(4))) float f32x4;
typedef __attribute__((ext_vector_type(4))) int int4v;
typedef __attribute__((ext_vector_type(4))) unsigned int uint4v;

__device__ __forceinline__ unsigned short f2bf(float x) {
  unsigned int u = __float_as_uint(x);
  unsigned int r = (u + 0x7fffu + ((u >> 16) & 1u)) >> 16;
  return (unsigned short)r;
}

__device__ __forceinline__ float bf2f(unsigned short v) {
  return __uint_as_float(((unsigned)v) << 16);
}

__device__ __forceinline__ void gload16(const void* g, void* l) {
  auto lp = (__attribute__((address_space(3))) void*)l;
  auto gp = (const __attribute__((address_space(1))) void*)g;
  __builtin_amdgcn_global_load_lds(gp, lp, 16, 0, 0);
}

// ---------------------------------------------------------------------------
// k0: WT bf16 [i=128][k=256] from W f32 [k][i] (LDS transpose). Grid 8.
// ---------------------------------------------------------------------------
__global__ __launch_bounds__(256) void k0_prep(
    const float* __restrict__ W, unsigned short* __restrict__ WT) {
  __shared__ float lw[32][132];
  int t = threadIdx.x;
  int kc0 = blockIdx.x * 32;
#pragma unroll
  for (int m = 0; m < 4; ++m) {
    int idx = t * 16 + m * 4;
    f32x4 v = *(const f32x4*)(W + kc0 * 128 + idx);
    int k = idx >> 7, i0 = idx & 127;
    *(f32x4*)&lw[k][i0] = v;
  }
  __syncthreads();
  int i = t >> 1, half = t & 1;
  unsigned short pk[16];
#pragma unroll
  for (int kk = 0; kk < 16; ++kk) pk[kk] = f2bf(lw[half * 16 + kk][i]);
  ushort8* dst = (ushort8*)(WT + i * 256 + kc0 + half * 16);
  dst[0] = *(ushort8*)&pk[0];
  dst[1] = *(ushort8*)&pk[8];
}

// ---------------------------------------------------------------------------
// k1b: Wh via mfma_16x16x32_bf16. 16-row blocks, grid 1024.
// Emits whT bf16 [b][i=128][n=4096] AND s1L/s2L (x log2 e).
// ---------------------------------------------------------------------------
__global__ __launch_bounds__(256) void k1b_wh(
    const float* __restrict__ h, const unsigned short* __restrict__ WT,
    const float* __restrict__ a, unsigned short* __restrict__ whT,
    float* __restrict__ s1L, float* __restrict__ s2L) {
  __shared__ __align__(16) char smem[36864];
  int t = threadIdx.x;
  int w = t >> 6, l = t & 63, g = l >> 4, r = l & 15;
  int r0 = blockIdx.x * 16;
  int b = r0 >> 12, nbase = r0 & 4095;

  f32x4 acc[2];
  acc[0] = (f32x4){0.f, 0.f, 0.f, 0.f};
  acc[1] = (f32x4){0.f, 0.f, 0.f, 0.f};

  for (int kc = 0; kc < 2; ++kc) {
    __syncthreads();
    {
      int row = t >> 4, sec = t & 15;
      const f32x4* src =
          (const f32x4*)(h + (long long)(r0 + row) * 256 + kc * 128 + sec * 8);
      f32x4 v0 = src[0], v1 = src[1];
      unsigned int pk[4];
      pk[0] = ((unsigned)f2bf(v0.y) << 16) | f2bf(v0.x);
      pk[1] = ((unsigned)f2bf(v0.w) << 16) | f2bf(v0.z);
      pk[2] = ((unsigned)f2bf(v1.y) << 16) | f2bf(v1.x);
      pk[3] = ((unsigned)f2bf(v1.w) << 16) | f2bf(v1.z);
      *(ushort8*)(smem + row * 256 + ((sec ^ (row & 7)) << 4)) = *(ushort8*)pk;
    }
    {
      int i = t >> 1, pt = t & 1;
      const ushort8* src = (const ushort8*)(WT + i * 256 + kc * 128 + pt * 64);
#pragma unroll
      for (int m = 0; m < 8; ++m) {
        ushort8 v = src[m];
        int slot = pt * 8 + m;
        *(ushort8*)(smem + 4096 + i * 256 + ((slot ^ (i & 7)) << 4)) = v;
      }
    }
    __syncthreads();
#pragma unroll
    for (int kk = 0; kk < 4; ++kk) {
      short8 af =
          *(const short8*)(smem + r * 256 + (((kk * 4 + g) ^ (r & 7)) << 4));
#pragma unroll
      for (int s = 0; s < 2; ++s) {
        int i = w * 32 + s * 16 + r;
        short8 bf = *(const short8*)(smem + 4096 + i * 256 +
                                     (((kk * 4 + g) ^ (i & 7)) << 4));
        acc[s] =
            __builtin_amdgcn_mfma_f32_16x16x32_bf16(af, bf, acc[s], 0, 0, 0);
      }
    }
  }

  __syncthreads();
  unsigned short* tb = (unsigned short*)smem;  // [128][25]
#pragma unroll
  for (int s = 0; s < 2; ++s)
#pragma unroll
    for (int q = 0; q < 4; ++q)
      tb[(w * 32 + s * 16 + r) * 25 + g * 4 + q] = f2bf(acc[s][q]);
  __syncthreads();

  {
    int i = t >> 1, half = t & 1;
    ushort8 v = *(const ushort8*)(tb + i * 25 + half * 8);
    *(ushort8*)(whT + (((long long)(b * 128 + i)) << 12) + nbase + half * 8) =
        v;
  }
  {
    int n = t >> 4, seg = t & 15;
    f32x4 a10 = *(const f32x4*)(a + seg * 8);
    f32x4 a11 = *(const f32x4*)(a + seg * 8 + 4);
    f32x4 a20 = *(const f32x4*)(a + 128 + seg * 8);
    f32x4 a21 = *(const f32x4*)(a + 128 + seg * 8 + 4);
    float v1 = 0.f, v2 = 0.f;
#pragma unroll
    for (int m = 0; m < 8; ++m) {
      float wh = bf2f(tb[(seg * 8 + m) * 25 + n]);
      float c1 = (m < 4) ? a10[m] : a11[m - 4];
      float c2 = (m < 4) ? a20[m] : a21[m - 4];
      v1 += wh * c1;
      v2 += wh * c2;
    }
#pragma unroll
    for (int off = 8; off; off >>= 1) {
      v1 += __shfl_xor(v1, off);
      v2 += __shfl_xor(v2, off);
    }
    if (seg == 0) {
      s1L[r0 + n] = v1 * L2E;
      s2L[r0 + n] = v2 * L2E;
    }
  }
}

// ---------------------------------------------------------------------------
// k2: block-per-row, coalesced NT int4 adj loads, single-pass no-max softmax
// in exp2 domain; mask via shfl_xor nibble merge. st2[row] = {E1, E2} where
// E1 = exp2(s1L+negc), E2 = exp2(ALPHA*s1L+negc) -- factorized for k3.
// ---------------------------------------------------------------------------
__global__ __launch_bounds__(256) void k2_stats(
    const int* __restrict__ adj, const float* __restrict__ s1L,
    const float* __restrict__ s2L, float2* __restrict__ st2,
    unsigned long long* __restrict__ mask64) {
  __shared__ unsigned int mwords[128];
  __shared__ float wsum[4];
  int row = blockIdx.x;
  int b = row >> 12;
  int t = threadIdx.x;
  float s1j = s1L[row];
  const int4v* arow = (const int4v*)(adj + (long long)row * Nn);
  const f32x4* s2v = (const f32x4*)(s2L + (b << 12));

  float sum = 0.f;
#pragma unroll
  for (int q = 0; q < 4; ++q) {
    int4v av = __builtin_nontemporal_load(arow + q * 256 + t);
    f32x4 sv = s2v[q * 256 + t];
    unsigned nib = 0;
#pragma unroll
    for (int c = 0; c < 4; ++c) {
      float u = s1j + sv[c];
      float vL = fmaxf(u, ALPHA * u);
      float e = exp2f(vL);
      sum = fmaf((float)av[c], e, sum);  // adj in {0,1}
      nib |= ((unsigned)av[c]) << c;
    }
    unsigned n1 = nib | (__shfl_xor(nib, 1) << 4);
    unsigned n2 = n1 | (__shfl_xor(n1, 2) << 8);
    unsigned n4 = n2 | (__shfl_xor(n2, 4) << 16);
    if ((t & 7) == 0) mwords[q * 32 + (t >> 3)] = n4;
  }
#pragma unroll
  for (int off = 32; off; off >>= 1) sum += __shfl_xor(sum, off);
  if ((t & 63) == 0) wsum[t >> 6] = sum;
  __syncthreads();
  if (t < 64) {
    unsigned long long mv = *(unsigned long long*)&mwords[t * 2];
    mask64[((long long)row << 6) + t] = mv;
  }
  if (t == 0) {
    float S = wsum[0] + wsum[1] + wsum[2] + wsum[3];
    float negc = (S > 0.f) ? -log2f(S) : -1.0e30f;
    st2[row] =
        make_float2(exp2f(s1j + negc), exp2f(ALPHA * s1j + negc));
  }
}

// ---------------------------------------------------------------------------
// k3: bf16 partial[jc][b][k][i] = sum_{j in eighth} p[j,k]*Wh[j,i].
// KT=256: each wave owns k=32 as TWO A-fragments sharing every B-fragment
// read -- 8 ds_read_b128 feed 16 MFMAs, halving LDS B traffic (R15 diag:
// LDS-pipe ~20us was a co-limiter with VALU) and halving whT L2 refetch.
// Grid 512 = 4b x 8jc x 16kt (all 8 jc of (b,kt) share an XCD).
// LDS 36KB: whT dbuf 2x8K @0, mask planes mk[8][512] @16K, stl @32K.
// acc 64 VGPR -> 4 waves/SIMD.
// ---------------------------------------------------------------------------
__global__ __launch_bounds__(512, 4) void k3_pv(
    const unsigned short* __restrict__ whT, const float2* __restrict__ st2,
    const unsigned long long* __restrict__ mask64,
    const float* __restrict__ s2L, unsigned short* __restrict__ pbuf) {
  __shared__ __align__(16) char smem[36864];
  unsigned int* mkpl = (unsigned int*)(smem + 16384);  // [8][512]
  float2* stl = (float2*)(smem + 32768);               // [512]

  int t = threadIdx.x;
  int orig = blockIdx.x;
  int x = orig & 7, mm = orig >> 3;      // mm 0..63
  int b = x >> 1;
  int kt = ((x & 1) << 3) | (mm & 7);    // 0..15
  int jc = mm >> 3;                      // 0..7
  int w = t >> 6, l = t & 63;
  int lh = l >> 4;   // 0..3: j-subgroup (A/B K-group)
  int lo = l & 15;   // 0..15: A-row (k) / B-col (i)
  int ks = w;        // 8 k-subs x 32
  int jq0 = jc * JQ;
  long long brow = (long long)(b << 12);
  int k0g = kt << 8;  // KT = 256
  float z1a = s2L[brow + k0g + ks * 32 + lo];
  float z1b = s2L[brow + k0g + ks * 32 + 16 + lo];
  float F1a = exp2f(z1a), F2a = exp2f(ALPHA * z1a);
  float F1b = exp2f(z1b), F2b = exp2f(ALPHA * z1b);
  int shA = 31 - lo;  // bit lo of the ks-plane word
  int shB = 15 - lo;  // bit 16+lo

  // stage-once: stl (4KB via gload16), 8 mask planes (reg-staged scatter)
  if (t < 256) gload16(st2 + brow + jq0 + t * 2, (char*)stl + t * 16);
  {
    const char* msrc =
        (const char*)(mask64 + ((brow + jq0 + t) << 6)) + kt * 32;
    uint4v m0 = *(const uint4v*)msrc;
    uint4v m1 = *(const uint4v*)(msrc + 16);
    mkpl[0 * 512 + t] = m0[0];
    mkpl[1 * 512 + t] = m0[1];
    mkpl[2 * 512 + t] = m0[2];
    mkpl[3 * 512 + t] = m0[3];
    mkpl[4 * 512 + t] = m1[0];
    mkpl[5 * 512 + t] = m1[1];
    mkpl[6 * 512 + t] = m1[2];
    mkpl[7 * 512 + t] = m1[3];
  }
  // whT chunk 0: thread t -> granule (gj=t>>7 j-oct, gi=t&127 i), linear dest
  const unsigned short* whTb = whT + ((long long)b << 19);
  int gi = t & 127;
  const unsigned short* wsrc0 =
      whTb + (long long)gi * 4096 + jq0 + (t >> 7) * 8;
  gload16(wsrc0, smem + t * 16);
  __syncthreads();

  f32x4 accA[8], accB[8];
#pragma unroll
  for (int q = 0; q < 8; ++q) {
    accA[q] = (f32x4){0.f, 0.f, 0.f, 0.f};
    accB[q] = (f32x4){0.f, 0.f, 0.f, 0.f};
  }

  const unsigned int* mkw = mkpl + ks * 512;
#pragma unroll 1
  for (int ch = 0; ch < NCH; ++ch) {
    int cur = ch & 1;
    if (ch + 1 < NCH)
      gload16(wsrc0 + (ch + 1) * 32, smem + (cur ^ 1) * 8192 + t * 16);
    char* wb = smem + cur * 8192;
    int jb = ch * 32 + lh * 8;  // this lane-group's 8 j's
    uint4v mw0 = *(const uint4v*)(mkw + jb);
    uint4v mw1 = *(const uint4v*)(mkw + jb + 4);
    const f32x4* stp = (const f32x4*)(stl + jb);  // 16B-aligned (jb mult of 8)
    f32x4 sA = stp[0], sB = stp[1], sC = stp[2], sD = stp[3];
    short8 afA, afB;
#pragma unroll
    for (int e = 0; e < 8; ++e) {
      f32x4 sv = (e < 2) ? sA : (e < 4) ? sB : (e < 6) ? sC : sD;
      float E1 = (e & 1) ? sv.z : sv.x;
      float E2 = (e & 1) ? sv.w : sv.y;
      unsigned mv = (e < 4) ? mw0[e] : mw1[e - 4];
      float pA = fmaxf(E1 * F1a, E2 * F2a);
      float pB = fmaxf(E1 * F1b, E2 * F2b);
      int mA = ((int)(mv << shA)) >> 31;
      int mB = ((int)(mv << shB)) >> 31;
      unsigned puA = __float_as_uint(pA) & (unsigned)mA;
      unsigned puB = __float_as_uint(pB) & (unsigned)mB;
      __hip_bfloat16 hA = __float2bfloat16(__uint_as_float(puA));
      __hip_bfloat16 hB = __float2bfloat16(__uint_as_float(puB));
      afA[e] = *(short*)&hA;
      afB[e] = *(short*)&hB;
    }
#pragma unroll
    for (int q = 0; q < 8; ++q) {
      short8 bv = *(const short8*)(wb + ((lh * 128 + q * 16 + lo) << 4));
      accA[q] =
          __builtin_amdgcn_mfma_f32_16x16x32_bf16(afA, bv, accA[q], 0, 0, 0);
      accB[q] =
          __builtin_amdgcn_mfma_f32_16x16x32_bf16(afB, bv, accB[q], 0, 0, 0);
    }
    __syncthreads();
  }

  // store: D col = lo (i within tile), rows: ktile0 = ks*32 + lh*4 + r,
  // ktile1 = ks*32 + 16 + lh*4 + r
  unsigned short* pb = pbuf + (long long)jc * SLAB + ((brow + k0g) << 7);
#pragma unroll
  for (int q = 0; q < 8; ++q) {
#pragma unroll
    for (int r = 0; r < 4; ++r) {
      int klA = ks * 32 + lh * 4 + r;
      int klB = klA + 16;
      __hip_bfloat16 hA = __float2bfloat16(accA[q][r]);
      __hip_bfloat16 hB = __float2bfloat16(accB[q][r]);
      pb[klA * 128 + q * 16 + lo] = *(unsigned short*)&hA;
      pb[klB * 128 + q * 16 + lo] = *(unsigned short*)&hB;
    }
  }
}

// ---------------------------------------------------------------------------
// k4: out = elu(sum_jc bf16 partial). Grid 1024 x 256, 8 elems/thread.
// Swizzle reads tile n from the XCD (n>>7) where k3 wrote it.
// ---------------------------------------------------------------------------
__global__ __launch_bounds__(256) void k4_reduce(
    const unsigned short* __restrict__ pbuf, float* __restrict__ out) {
  int orig = blockIdx.x;
  int n = (orig & 7) * 128 + (orig >> 3);  // bijective (1024 % 8 == 0)
  int base = (n * 256 + threadIdx.x) * 8;
  float s[8] = {0.f, 0.f, 0.f, 0.f, 0.f, 0.f, 0.f, 0.f};
#pragma unroll
  for (int sl = 0; sl < JC; ++sl) {
    ushort8 v = *(const ushort8*)(pbuf + (long long)sl * SLAB + base);
#pragma unroll
    for (int e = 0; e < 8; ++e)
      s[e] += __uint_as_float(((unsigned)(unsigned short)v[e]) << 16);
  }
  f32x4 o0, o1;
#pragma unroll
  for (int e = 0; e < 8; ++e) {
    float xv = s[e];
    float y = xv > 0.f ? xv : expm1f(xv);
    if (e < 4) o0[e] = y; else o1[e - 4] = y;
  }
  *(f32x4*)(out + base) = o0;
  *(f32x4*)(out + base + 4) = o1;
}

extern "C" void kernel_launch(void* const* d_in, const int* in_sizes, int n_in,
                              void* d_out, int out_size, void* d_ws,
                              size_t ws_size, hipStream_t stream) {
  const float* h = (const float*)d_in[0];
  const int* adj = (const int*)d_in[1];
  const float* W = (const float*)d_in[2];
  const float* a = (const float*)d_in[3];
  float* out = (float*)d_out;

  char* ws = (char*)d_ws;
  unsigned short* WT = (unsigned short*)ws;                  // 64 KB
  unsigned short* whT = (unsigned short*)(ws + (1 << 20));   // 4 MB
  float* s1L = (float*)(ws + (5 << 20));                     // 64 KB
  float* s2L = s1L + 16384;                                  // 64 KB
  float2* st2 = (float2*)(ws + (5 << 20) + (128 << 10));     // 128 KB
  unsigned long long* mask64 =
      (unsigned long long*)(ws + (6 << 20));                 // 8 MB
  unsigned short* pbuf = (unsigned short*)(ws + (16 << 20)); // 32 MB bf16

  hipLaunchKernelGGL(k0_prep, dim3(8), dim3(256), 0, stream, W, WT);
  hipLaunchKernelGGL(k1b_wh, dim3(1024), dim3(256), 0, stream, h, WT, a, whT,
                     s1L, s2L);
  hipLaunchKernelGGL(k2_stats, dim3(16384), dim3(256), 0, stream, adj, s1L,
                     s2L, st2, mask64);
  hipLaunchKernelGGL(k3_pv, dim3(512), dim3(512), 0, stream, whT, st2,
                     mask64, s2L, pbuf);
  hipLaunchKernelGGL(k4_reduce, dim3(1024), dim3(256), 0, stream, pbuf, out);
}